// Round 6
// baseline (2464.799 us; speedup 1.0000x reference)
//
#include <hip/hip_runtime.h>

#define NTOK 65536
#define DDIM 512
#define HDIM 1024
#define NEXP 8
#define PROJ 256
#define CAP  16384
#define NSLOT (2*NTOK)
#define LOG100 4.605170185988091f

typedef __attribute__((ext_vector_type(8))) short bf16x8;
typedef __attribute__((ext_vector_type(4))) short short4v;
typedef __attribute__((ext_vector_type(4))) float f32x4;

// ---------- helpers ----------
__device__ inline float bf2f(unsigned short u){
    union { float f; unsigned int i; } c; c.i = ((unsigned int)u) << 16; return c.f;
}
__device__ inline unsigned short f2bf(float f){
    union { float f; unsigned int i; } c; c.f = f;
    unsigned int x = c.i;
    return (unsigned short)((x + 0x7fffu + ((x >> 16) & 1u)) >> 16); // RTNE
}
__device__ inline void gload16(const void* g, void* lds){
    __builtin_amdgcn_global_load_lds(
        (const __attribute__((address_space(1))) unsigned int*)g,
        (__attribute__((address_space(3))) unsigned int*)lds, 16, 0, 0);
}

__global__ void zero_k(float4* __restrict__ p){
    p[(long)blockIdx.x * 256 + threadIdx.x] = float4{0.f, 0.f, 0.f, 0.f};
}

__global__ void cvt_k(const float4* __restrict__ src, ushort4* __restrict__ dst, int n4){
    int i = blockIdx.x * 256 + threadIdx.x;
    if (i < n4){
        float4 f = src[i];
        ushort4 u; u.x = f2bf(f.x); u.y = f2bf(f.y); u.z = f2bf(f.z); u.w = f2bf(f.w);
        dst[i] = u;
    }
}

// ---------- batched transpose+convert: z<8 -> W1 expert z, z>=8 -> W2 expert z-8 ----------
__global__ __launch_bounds__(256)
void trans2_k(const float* __restrict__ W1, const float* __restrict__ W2,
              unsigned short* __restrict__ W1T, unsigned short* __restrict__ W2T)
{
    int z = blockIdx.z;
    const float* in; unsigned short* out; int R, C;
    if (z < 8){ in = W1 + (size_t)z*DDIM*HDIM; out = W1T + (size_t)z*DDIM*HDIM; R = DDIM; C = HDIM; }
    else      { in = W2 + (size_t)(z-8)*DDIM*HDIM; out = W2T + (size_t)(z-8)*DDIM*HDIM; R = HDIM; C = DDIM; }
    int rbase = blockIdx.y * 32, cbase = blockIdx.x * 32;
    if (rbase >= R || cbase >= C) return;
    __shared__ float tile[32][33];
    int tx = threadIdx.x, ty = threadIdx.y;   // (32,8)
    #pragma unroll
    for (int i = 0; i < 4; i++)
        tile[ty + i*8][tx] = in[(long)(rbase + ty + i*8) * C + cbase + tx];
    __syncthreads();
    #pragma unroll
    for (int i = 0; i < 4; i++)
        out[(long)(cbase + ty + i*8) * R + rbase + tx] = f2bf(tile[tx][ty + i*8]);
}

// ---------- normalize sim columns, batched over 3 models ----------
struct SimArgs { const float* sim[3]; };

__global__ void simn3_k(SimArgs sa, float* __restrict__ simn3){
    __shared__ float red[256];
    const float* sim = sa.sim[blockIdx.x];
    float* simn = simn3 + (size_t)blockIdx.x * PROJ * NEXP;
    int j = threadIdx.x;
    for (int e = 0; e < NEXP; e++){
        float v = sim[j*NEXP + e];
        red[j] = v*v;
        __syncthreads();
        for (int s = 128; s > 0; s >>= 1){
            if (j < s) red[j] += red[j + s];
            __syncthreads();
        }
        float nrm = sqrtf(red[0]) + 1e-12f;
        __syncthreads();
        simn[j*NEXP + e] = v / nrm;
    }
}

// ---------- fused projection + gate: 64 tok x 256 cols, BK=16 (29KB LDS) ----------
struct GateArgs { const float* Wp[3]; const float* bp[3]; const float* sn[3]; const float* tp[3]; };

__global__ __launch_bounds__(256)
void pgate3_k(const float* __restrict__ x, const int* __restrict__ label,
              GateArgs ga, int* __restrict__ idx3, float* __restrict__ gw3)
{
    const int m = blockIdx.y;
    const int n0 = blockIdx.x * 64;
    const float* Wp = ga.Wp[m];

    __shared__ __align__(16) float As[16][64];     // [k][token] 4KB
    __shared__ __align__(16) float Bs[16][256];    // [k][col] swizzled float4 slots, 16KB
    __shared__ float Sn[PROJ*NEXP];                // 8KB
    __shared__ float Bp[PROJ];                     // 1KB

    const int t = threadIdx.x;
    for (int i = t; i < PROJ*NEXP; i += 256) Sn[i] = ga.sn[m][i];
    Bp[t] = ga.bp[m][t];

    const int tn = t & 15;      // col group: cols tn*16 .. tn*16+15
    const int tmq = t >> 4;     // token group: tokens tmq*4 .. tmq*4+3
    int bidx[4];
    #pragma unroll
    for (int j = 0; j < 4; j++){ int s = tn*4 + j; bidx[j] = s ^ ((s >> 3) & 7); }

    const int arow = t & 63, akc = (t >> 6) * 4;
    const float* aptr = x + (long)(n0 + arow) * DDIM + akc;
    const int bs = t & 63, bk0 = t >> 6;
    const int bphys = bs ^ ((bs >> 3) & 7);

    float acc[4][16];
    #pragma unroll
    for (int a = 0; a < 4; a++)
        #pragma unroll
        for (int i = 0; i < 16; i++) acc[a][i] = 0.f;

    for (int k0 = 0; k0 < DDIM; k0 += 16){
        __syncthreads();
        {   // A stage: transposed scalar writes (2 lanes/bank = free)
            float4 a0 = *(const float4*)(aptr + k0);
            As[akc+0][arow] = a0.x; As[akc+1][arow] = a0.y;
            As[akc+2][arow] = a0.z; As[akc+3][arow] = a0.w;
        }
        #pragma unroll
        for (int i = 0; i < 4; i++){   // B stage: coalesced rows, swizzled slots
            int kk = bk0 + i*4;
            float4 bv = *(const float4*)(Wp + (long)(k0 + kk) * PROJ + bs*4);
            *(float4*)&Bs[kk][bphys*4] = bv;
        }
        __syncthreads();
        #pragma unroll
        for (int kk = 0; kk < 16; kk++){
            float4 a4 = *(const float4*)&As[kk][tmq*4];
            #pragma unroll
            for (int j = 0; j < 4; j++){
                float4 b = *(const float4*)&Bs[kk][bidx[j]*4];
                #pragma unroll
                for (int ai = 0; ai < 4; ai++){
                    float av = (ai==0)?a4.x:(ai==1)?a4.y:(ai==2)?a4.z:a4.w;
                    acc[ai][j*4+0] = fmaf(av, b.x, acc[ai][j*4+0]);
                    acc[ai][j*4+1] = fmaf(av, b.y, acc[ai][j*4+1]);
                    acc[ai][j*4+2] = fmaf(av, b.z, acc[ai][j*4+2]);
                    acc[ai][j*4+3] = fmaf(av, b.w, acc[ai][j*4+3]);
                }
            }
        }
    }

    // epilogue: bias + per-thread partial l2/dot sums over 16 cols x 4 tokens
    float ss[4] = {0.f, 0.f, 0.f, 0.f};
    float dots[4][8];
    #pragma unroll
    for (int a = 0; a < 4; a++)
        #pragma unroll
        for (int e = 0; e < 8; e++) dots[a][e] = 0.f;

    #pragma unroll
    for (int j = 0; j < 4; j++)
        #pragma unroll
        for (int w = 0; w < 4; w++){
            int col = tn*16 + j*4 + w;
            float bias = Bp[col];
            float sn[8];
            *(float4*)(sn)   = *(const float4*)&Sn[col*8];
            *(float4*)(sn+4) = *(const float4*)&Sn[col*8+4];
            #pragma unroll
            for (int ai = 0; ai < 4; ai++){
                float p = acc[ai][j*4+w] + bias;
                ss[ai] = fmaf(p, p, ss[ai]);
                #pragma unroll
                for (int e = 0; e < 8; e++) dots[ai][e] = fmaf(p, sn[e], dots[ai][e]);
            }
        }
    #pragma unroll
    for (int o = 1; o <= 8; o <<= 1){
        #pragma unroll
        for (int ai = 0; ai < 4; ai++){
            ss[ai] += __shfl_xor(ss[ai], o, 64);
            #pragma unroll
            for (int e = 0; e < 8; e++) dots[ai][e] += __shfl_xor(dots[ai][e], o, 64);
        }
    }
    if (tn == 0){
        float scale = expf(fminf(ga.tp[m][0], LOG100));
        #pragma unroll
        for (int ai = 0; ai < 4; ai++){
            int n = n0 + tmq*4 + ai;
            float inv = scale / (sqrtf(ss[ai]) + 1e-12f);
            float l[8], mx = -1e30f;
            #pragma unroll
            for (int e = 0; e < 8; e++){ l[e] = dots[ai][e] * inv; mx = fmaxf(mx, l[e]); }
            float g[8], s = 0.f;
            #pragma unroll
            for (int e = 0; e < 8; e++){ g[e] = expf(l[e] - mx); s += g[e]; }
            #pragma unroll
            for (int e = 0; e < 8; e++) g[e] /= s;
            int e0 = 0; float b0 = g[0];
            #pragma unroll
            for (int e = 1; e < 8; e++) if (g[e] > b0){ b0 = g[e]; e0 = e; }
            int e1 = (e0 == 0) ? 1 : 0; float b1v = g[e1];
            #pragma unroll
            for (int e = 0; e < 8; e++) if (e != e0 && g[e] > b1v){ b1v = g[e]; e1 = e; }
            float maskv = (m == 0) ? 1.f : ((label[n] == m - 1) ? 1.f : 0.f);
            float s2 = b0 + b1v + 1e-9f;
            long base = (long)m * NSLOT + 2*n;
            gw3[base]   = b0 / s2 * maskv;
            gw3[base+1] = b1v / s2 * maskv;
            idx3[base]   = e0;
            idx3[base+1] = e1;
        }
    }
}

// ---------- transposed-output bf16 MFMA GEMM core, 128x128, BK=32 ----------
// A = weights [Mtot][Kd] bf16 (k-contiguous). B = activations [*][Kd] rows by slot
// (optionally gathered, optionally fp32 with reg-stage convert).
// C(m,n): m = output feature (contiguous in buffer), n = capacity slot.
// OMODE 1: h store  h[s][m..m+3] = ushort4(relu(acc+b1))
// OMODE 3: out RMW  out[tok[s]][m..m+3] += g * (acc + b2)   (float4)
template<int BFP32, int BGATHER, int OMODE>
__device__ __forceinline__
void gemm_core_t(short* As, short* Bs,
                 const unsigned short* __restrict__ AT, const void* __restrict__ Bv,
                 const float* __restrict__ bias, void* __restrict__ Cout,
                 int Kd, int Mld, int row0, int col0, int limitN,
                 const int* __restrict__ rowidx, const int* __restrict__ otok,
                 const float* __restrict__ gs)
{
    const int t = threadIdx.x;
    const int w = t >> 6, l = t & 63;
    const int qrow = l >> 2;
    const int kc = (l & 3) * 8;

    long arowg[2];
    #pragma unroll
    for (int q = 0; q < 2; q++)
        arowg[q] = (long)(row0 + w*32 + q*16 + qrow) * Kd;

    long browg[2];
    if (!BFP32){
        #pragma unroll
        for (int q = 0; q < 2; q++){
            int s = col0 + w*32 + q*16 + qrow;
            int gi = s;
            if (BGATHER) gi = (s < limitN) ? rowidx[s] : 0;
            browg[q] = (long)gi * Kd;
        }
    }
    // fp32-B fallback staging geometry
    const int sbr = t >> 1, sbc = (t & 1) * 16;
    long bbase_f = 0;
    if (BFP32){
        int s = col0 + sbr;
        int gi = s;
        if (BGATHER) gi = (s < limitN) ? rowidx[s] : 0;
        bbase_f = (long)gi * Kd;
    }

    const int wm = (w >> 1) * 64, wn = (w & 1) * 64;
    const int fr = l & 15, fk = l >> 4;
    const int koff = fk * 8, fk4 = fk * 4;

    f32x4 acc[4][4];
    #pragma unroll
    for (int i = 0; i < 4; i++)
        #pragma unroll
        for (int j = 0; j < 4; j++) acc[i][j] = (f32x4){0.f, 0.f, 0.f, 0.f};

    for (int k0 = 0; k0 < Kd; k0 += 32){
        __syncthreads();
        #pragma unroll
        for (int q = 0; q < 2; q++)
            gload16(AT + arowg[q] + k0 + kc, As + w*1024 + q*512);
        if (BFP32){
            const float* bp = (const float*)Bv + bbase_f + k0 + sbc;
            float4 f0 = *(const float4*)(bp);
            float4 f1 = *(const float4*)(bp + 4);
            float4 f2 = *(const float4*)(bp + 8);
            float4 f3 = *(const float4*)(bp + 12);
            short* dst = Bs + sbr*32 + sbc;
            *(short4v*)(dst+ 0) = (short4v){(short)f2bf(f0.x),(short)f2bf(f0.y),(short)f2bf(f0.z),(short)f2bf(f0.w)};
            *(short4v*)(dst+ 4) = (short4v){(short)f2bf(f1.x),(short)f2bf(f1.y),(short)f2bf(f1.z),(short)f2bf(f1.w)};
            *(short4v*)(dst+ 8) = (short4v){(short)f2bf(f2.x),(short)f2bf(f2.y),(short)f2bf(f2.z),(short)f2bf(f2.w)};
            *(short4v*)(dst+12) = (short4v){(short)f2bf(f3.x),(short)f2bf(f3.y),(short)f2bf(f3.z),(short)f2bf(f3.w)};
        } else {
            const unsigned short* bp = (const unsigned short*)Bv;
            #pragma unroll
            for (int q = 0; q < 2; q++)
                gload16(bp + browg[q] + k0 + kc, Bs + w*1024 + q*512);
        }
        __syncthreads();

        bf16x8 af[4], bfv[4];
        #pragma unroll
        for (int i = 0; i < 4; i++) af[i]  = *(const bf16x8*)&As[(wm + i*16 + fr)*32 + koff];
        #pragma unroll
        for (int j = 0; j < 4; j++) bfv[j] = *(const bf16x8*)&Bs[(wn + j*16 + fr)*32 + koff];
        #pragma unroll
        for (int i = 0; i < 4; i++)
            #pragma unroll
            for (int j = 0; j < 4; j++)
                acc[i][j] = __builtin_amdgcn_mfma_f32_16x16x32_bf16(af[i], bfv[j], acc[i][j], 0, 0, 0);
    }

    // vectorized epilogue: 4 consecutive M-rows per lane = contiguous output
    #pragma unroll
    for (int i = 0; i < 4; i++){
        const int mc = row0 + wm + i*16 + fk4;
        float4 bb = *(const float4*)(bias + mc);
        #pragma unroll
        for (int j = 0; j < 4; j++){
            int s = col0 + wn + j*16 + fr;
            if (s < limitN){
                if (OMODE == 1){
                    ushort4 u;
                    u.x = f2bf(fmaxf(acc[i][j][0] + bb.x, 0.f));
                    u.y = f2bf(fmaxf(acc[i][j][1] + bb.y, 0.f));
                    u.z = f2bf(fmaxf(acc[i][j][2] + bb.z, 0.f));
                    u.w = f2bf(fmaxf(acc[i][j][3] + bb.w, 0.f));
                    *(ushort4*)((unsigned short*)Cout + (long)s * Mld + mc) = u;
                } else {
                    int tk = otok[s];
                    float g = gs[s];
                    float* op = (float*)Cout + (long)tk * Mld + mc;
                    float4 c = *(const float4*)op;
                    c.x += g * (acc[i][j][0] + bb.x);
                    c.y += g * (acc[i][j][1] + bb.y);
                    c.z += g * (acc[i][j][2] + bb.z);
                    c.w += g * (acc[i][j][3] + bb.w);
                    *(float4*)op = c;   // race-free: distinct tokens per expert, disjoint m-ranges
                }
            }
        }
    }
}

template<int BFP32, int BGATHER, int OMODE>
__global__ __launch_bounds__(256)
void mgemm3_k(const unsigned short* __restrict__ AT, const void* __restrict__ Bv,
              const float* __restrict__ bias, void* __restrict__ Cout,
              int Kd, int Mld,
              const int* __restrict__ rowidx, const int* __restrict__ otok,
              const float* __restrict__ gs, const int* __restrict__ cntp, int cnti)
{
    __shared__ __align__(16) short As[128*32];
    __shared__ __align__(16) short Bs[128*32];
    int limit = cntp[cnti]; if (limit > CAP) limit = CAP;
    int row0 = blockIdx.x * 128, col0 = blockIdx.y * 128;
    if (col0 >= limit) return;
    gemm_core_t<BFP32, BGATHER, OMODE>(As, Bs, AT, Bv, bias, Cout, Kd, Mld,
                                       row0, col0, limit, rowidx, otok, gs);
}

// ---------- pipelined dual-role FFN step: bx<8 h-GEMM(eh), bx>=8 y-GEMM(eh-1) ----------
template<int BFP32>
__global__ __launch_bounds__(256)
void ffn2_k(const void* __restrict__ xsrc,
            const unsigned short* __restrict__ W1T, const float* __restrict__ b1,
            const unsigned short* __restrict__ W2T, const float* __restrict__ b2,
            unsigned short* __restrict__ h0, unsigned short* __restrict__ h1,
            float* __restrict__ out,
            const int* __restrict__ tok, const float* __restrict__ gslot,
            const int* __restrict__ cntk, int eh)
{
    __shared__ __align__(16) short As[128*32];
    __shared__ __align__(16) short Bs[128*32];
    const int bx = blockIdx.x;
    const int col0 = blockIdx.y * 128;
    if (bx < 8){
        if (eh > 7) return;
        int limit = cntk[eh]; if (limit > CAP) limit = CAP;
        if (col0 >= limit) return;
        unsigned short* hd = (eh & 1) ? h1 : h0;
        gemm_core_t<BFP32, 1, 1>(As, Bs, W1T + (size_t)eh*HDIM*DDIM, xsrc,
                                 b1 + (size_t)eh*HDIM, hd, DDIM, HDIM,
                                 bx*128, col0, limit, tok + (size_t)eh*CAP, nullptr, nullptr);
    } else {
        int ey = eh - 1; if (ey < 0) return;
        int limit = cntk[ey]; if (limit > CAP) limit = CAP;
        if (col0 >= limit) return;
        const unsigned short* hs = (ey & 1) ? h1 : h0;
        gemm_core_t<0, 0, 3>(As, Bs, W2T + (size_t)ey*DDIM*HDIM, hs,
                             b2 + (size_t)ey*DDIM, out, HDIM, DDIM,
                             (bx-8)*128, col0, limit, nullptr,
                             tok + (size_t)ey*CAP, gslot + (size_t)ey*CAP);
    }
}

// ---------- ranking ----------
__global__ __launch_bounds__(1024)
void rank_count_k(const int* __restrict__ idx, const int* __restrict__ label, int mode,
                  int* __restrict__ bcnt)
{
    __shared__ int c[NEXP];
    int t = threadIdx.x;
    if (t < NEXP) c[t] = 0;
    __syncthreads();
    int s = blockIdx.x * 1024 + t;
    int n = s >> 1;
    int e = idx[s];
    bool valid = (mode == 0) || (label[n] == mode - 1);
    if (valid) atomicAdd(&c[e], 1);
    __syncthreads();
    if (t < NEXP) bcnt[blockIdx.x * NEXP + t] = c[t];
}

__global__ void rank_scan_k(const int* __restrict__ bcnt, int* __restrict__ boff,
                            int* __restrict__ cntk)
{
    int e = threadIdx.x;
    if (e < NEXP){
        int run = 0;
        for (int b = 0; b < NSLOT/1024; b++){
            boff[b * NEXP + e] = run;
            run += bcnt[b * NEXP + e];
        }
        cntk[e] = run < CAP ? run : CAP;
    }
}

__global__ __launch_bounds__(1024)
void rank_assign_k(const int* __restrict__ idx, const int* __restrict__ label, int mode,
                   const int* __restrict__ boff, const float* __restrict__ gw,
                   const float* __restrict__ dscale, int use_scale,
                   int* __restrict__ tok_of, float* __restrict__ gs_of)
{
    __shared__ int wcnt[16][NEXP];
    __shared__ int woff[16][NEXP];
    int t = threadIdx.x;
    int s = blockIdx.x * 1024 + t;
    int n = s >> 1;
    int e = idx[s];
    bool valid = (mode == 0) || (label[n] == mode - 1);
    int w = t >> 6, lane = t & 63;
    unsigned long long lt = (lane == 0) ? 0ull : ((1ull << lane) - 1ull);
    int myrank = 0;
    #pragma unroll
    for (int ei = 0; ei < NEXP; ei++){
        unsigned long long bal = __ballot(valid && (e == ei));
        if (ei == e) myrank = __popcll(bal & lt);
        if (lane == 0) wcnt[w][ei] = __popcll(bal);
    }
    __syncthreads();
    if (t < NEXP){
        int run = boff[blockIdx.x * NEXP + t];
        for (int w2 = 0; w2 < 16; w2++){
            woff[w2][t] = run;
            run += wcnt[w2][t];
        }
    }
    __syncthreads();
    int pos = woff[w][e] + myrank;
    bool keep = valid && (pos < CAP);
    if (keep){
        float scale = use_scale ? dscale[0] : 1.f;
        tok_of[e * CAP + pos] = n;
        gs_of[e * CAP + pos] = gw[s] * scale;
    }
}

extern "C" void kernel_launch(void* const* d_in, const int* in_sizes, int n_in,
                              void* d_out, int out_size, void* d_ws, size_t ws_size,
                              hipStream_t stream)
{
    (void)in_sizes; (void)n_in; (void)out_size;
    const float* x      = (const float*)d_in[0];
    const int*   label  = (const int*)  d_in[1];
    const float* dscale = (const float*)d_in[2];
    float* out = (float*)d_out;

    const size_t HS   = (size_t)CAP * HDIM * 2;             // 32MB per h slot
    const size_t WT2  = (size_t)2 * NEXP * DDIM * HDIM * 2; // 16MB
    const size_t XB   = (size_t)NTOK * DDIM * 2;            // 64MB
    const size_t SMALL = (size_t)3*PROJ*NEXP*4 + (size_t)3*NSLOT*4*2 +
                         (size_t)NEXP*CAP*4*2 + (size_t)(NSLOT/1024)*NEXP*4*2 + 256;
    const size_t base = HS + WT2 + SMALL;

    bool pip = false, useXb = false;
    if      (ws_size >= base + HS + XB){ pip = true; useXb = true; }
    else if (ws_size >= base + XB)     { useXb = true; }
    else if (ws_size >= base + HS)     { pip = true; }
    else if (ws_size < base) return;   // clean failure, not a fault

    char* p = (char*)d_ws;
    unsigned short* h0  = (unsigned short*)p; p += HS;
    unsigned short* W1T = (unsigned short*)p; p += WT2/2;
    unsigned short* W2T = (unsigned short*)p; p += WT2/2;
    float* simn3 = (float*)p;  p += (size_t)3*PROJ*NEXP*4;
    int*   idx3  = (int*)p;    p += (size_t)3*NSLOT*4;
    float* gw3   = (float*)p;  p += (size_t)3*NSLOT*4;
    int*   tok   = (int*)p;    p += (size_t)NEXP*CAP*4;
    float* gslot = (float*)p;  p += (size_t)NEXP*CAP*4;
    int*   bcnt  = (int*)p;    p += (size_t)(NSLOT/1024)*NEXP*4;
    int*   boff  = (int*)p;    p += (size_t)(NSLOT/1024)*NEXP*4;
    int*   cntk  = (int*)p;    p += 256;
    unsigned short* h1 = nullptr;
    unsigned short* xb = nullptr;
    if (pip){ h1 = (unsigned short*)p; p += HS; }
    if (useXb){ xb = (unsigned short*)p; }

    zero_k<<<dim3((NTOK*DDIM/4)/256), dim3(256), 0, stream>>>((float4*)out);
    if (useXb)
        cvt_k<<<dim3(NTOK*DDIM/4/256), dim3(256), 0, stream>>>((const float4*)x, (ushort4*)xb, NTOK*DDIM/4);

    GateArgs ga; SimArgs sa;
    for (int m = 0; m < 3; m++){
        ga.Wp[m] = (const float*)d_in[3 + 8*m + 0];
        ga.bp[m] = (const float*)d_in[3 + 8*m + 1];
        ga.sn[m] = simn3 + (size_t)m * PROJ * NEXP;
        ga.tp[m] = (const float*)d_in[3 + 8*m + 3];
        sa.sim[m] = (const float*)d_in[3 + 8*m + 2];
    }
    simn3_k<<<dim3(3), dim3(256), 0, stream>>>(sa, simn3);
    pgate3_k<<<dim3(NTOK/64, 3), dim3(256), 0, stream>>>(x, label, ga, idx3, gw3);

    for (int m = 0; m < 3; m++){
        const float* W1 = (const float*)d_in[3 + 8*m + 4];
        const float* b1 = (const float*)d_in[3 + 8*m + 5];
        const float* W2 = (const float*)d_in[3 + 8*m + 6];
        const float* b2 = (const float*)d_in[3 + 8*m + 7];
        const int* idxm = idx3 + (size_t)m * NSLOT;
        const float* gwm = gw3 + (size_t)m * NSLOT;

        trans2_k<<<dim3(32, 32, 16), dim3(32,8), 0, stream>>>(W1, W2, W1T, W2T);

        rank_count_k<<<dim3(NSLOT/1024), dim3(1024), 0, stream>>>(idxm, label, m, bcnt);
        rank_scan_k<<<dim3(1), dim3(64), 0, stream>>>(bcnt, boff, cntk);
        rank_assign_k<<<dim3(NSLOT/1024), dim3(1024), 0, stream>>>(
            idxm, label, m, boff, gwm, dscale, (m > 0) ? 1 : 0, tok, gslot);

        if (pip){
            for (int eh = 0; eh <= 8; eh++){
                if (useXb)
                    ffn2_k<0><<<dim3(12, CAP/128), 256, 0, stream>>>(
                        xb, W1T, b1, W2T, b2, h0, h1, out, tok, gslot, cntk, eh);
                else
                    ffn2_k<1><<<dim3(12, CAP/128), 256, 0, stream>>>(
                        x, W1T, b1, W2T, b2, h0, h1, out, tok, gslot, cntk, eh);
            }
        } else {
            for (int e = 0; e < NEXP; e++){
                if (useXb)
                    mgemm3_k<0, 1, 1><<<dim3(HDIM/128, CAP/128), 256, 0, stream>>>(
                        W1T + (size_t)e*HDIM*DDIM, xb, b1 + (size_t)e*HDIM, h0,
                        DDIM, HDIM, tok + (size_t)e*CAP, nullptr, nullptr, cntk, e);
                else
                    mgemm3_k<1, 1, 1><<<dim3(HDIM/128, CAP/128), 256, 0, stream>>>(
                        W1T + (size_t)e*HDIM*DDIM, x, b1 + (size_t)e*HDIM, h0,
                        DDIM, HDIM, tok + (size_t)e*CAP, nullptr, nullptr, cntk, e);
                mgemm3_k<0, 0, 3><<<dim3(DDIM/128, CAP/128), 256, 0, stream>>>(
                    W2T + (size_t)e*DDIM*HDIM, h0, b2 + (size_t)e*DDIM, out,
                    HDIM, DDIM, nullptr, tok + (size_t)e*CAP, gslot + (size_t)e*CAP, cntk, e);
            }
        }
    }
}

// Round 7
// 2351.090 us; speedup vs baseline: 1.0484x; 1.0484x over previous
//
#include <hip/hip_runtime.h>

#define NTOK 65536
#define DDIM 512
#define HDIM 1024
#define NEXP 8
#define PROJ 256
#define CAP  16384
#define NSLOT (2*NTOK)
#define LOG100 4.605170185988091f

typedef __attribute__((ext_vector_type(8))) short bf16x8;
typedef __attribute__((ext_vector_type(4))) short short4v;
typedef __attribute__((ext_vector_type(4))) float f32x4;

// ---------- helpers ----------
__device__ inline float bf2f(unsigned short u){
    union { float f; unsigned int i; } c; c.i = ((unsigned int)u) << 16; return c.f;
}
__device__ inline unsigned short f2bf(float f){
    union { float f; unsigned int i; } c; c.f = f;
    unsigned int x = c.i;
    return (unsigned short)((x + 0x7fffu + ((x >> 16) & 1u)) >> 16); // RTNE
}
__device__ inline void gload16(const void* g, void* lds){
    __builtin_amdgcn_global_load_lds(
        (const __attribute__((address_space(1))) unsigned int*)g,
        (__attribute__((address_space(3))) unsigned int*)lds, 16, 0, 0);
}

__global__ void zero_k(float4* __restrict__ p){
    p[(long)blockIdx.x * 256 + threadIdx.x] = float4{0.f, 0.f, 0.f, 0.f};
}

__global__ void cvt_k(const float4* __restrict__ src, ushort4* __restrict__ dst, int n4){
    int i = blockIdx.x * 256 + threadIdx.x;
    if (i < n4){
        float4 f = src[i];
        ushort4 u; u.x = f2bf(f.x); u.y = f2bf(f.y); u.z = f2bf(f.z); u.w = f2bf(f.w);
        dst[i] = u;
    }
}

// ---------- batched transpose+convert ----------
__global__ __launch_bounds__(256)
void trans2_k(const float* __restrict__ W1, const float* __restrict__ W2,
              unsigned short* __restrict__ W1T, unsigned short* __restrict__ W2T)
{
    int z = blockIdx.z;
    const float* in; unsigned short* out; int R, C;
    if (z < 8){ in = W1 + (size_t)z*DDIM*HDIM; out = W1T + (size_t)z*DDIM*HDIM; R = DDIM; C = HDIM; }
    else      { in = W2 + (size_t)(z-8)*DDIM*HDIM; out = W2T + (size_t)(z-8)*DDIM*HDIM; R = HDIM; C = DDIM; }
    int rbase = blockIdx.y * 32, cbase = blockIdx.x * 32;
    if (rbase >= R || cbase >= C) return;
    __shared__ float tile[32][33];
    int tx = threadIdx.x, ty = threadIdx.y;
    #pragma unroll
    for (int i = 0; i < 4; i++)
        tile[ty + i*8][tx] = in[(long)(rbase + ty + i*8) * C + cbase + tx];
    __syncthreads();
    #pragma unroll
    for (int i = 0; i < 4; i++)
        out[(long)(cbase + ty + i*8) * R + rbase + tx] = f2bf(tile[tx][ty + i*8]);
}

// ---------- normalize sim columns ----------
struct SimArgs { const float* sim[3]; };

__global__ void simn3_k(SimArgs sa, float* __restrict__ simn3){
    __shared__ float red[256];
    const float* sim = sa.sim[blockIdx.x];
    float* simn = simn3 + (size_t)blockIdx.x * PROJ * NEXP;
    int j = threadIdx.x;
    for (int e = 0; e < NEXP; e++){
        float v = sim[j*NEXP + e];
        red[j] = v*v;
        __syncthreads();
        for (int s = 128; s > 0; s >>= 1){
            if (j < s) red[j] += red[j + s];
            __syncthreads();
        }
        float nrm = sqrtf(red[0]) + 1e-12f;
        __syncthreads();
        simn[j*NEXP + e] = v / nrm;
    }
}

// ---------- fused projection + gate v4: 128 tok x 256 cols, BK=16, 8x16/thread ----------
struct GateArgs { const float* Wp[3]; const float* bp[3]; const float* sn[3]; const float* tp[3]; };

__global__ __launch_bounds__(256)
void pgate4_k(const float* __restrict__ x, const int* __restrict__ label,
              GateArgs ga, int* __restrict__ idx3, float* __restrict__ gw3)
{
    const int m = blockIdx.y;
    const int n0 = blockIdx.x * 128;
    const float* Wp = ga.Wp[m];

    __shared__ __align__(16) float As[16][128];    // [k][token] 8KB
    __shared__ __align__(16) float Bs[16][256];    // [k][col] swizzled float4 slots, 16KB
    __shared__ float Sn[PROJ*NEXP];                // 8KB
    __shared__ float Bp[PROJ];                     // 1KB

    const int t = threadIdx.x;
    for (int i = t; i < PROJ*NEXP; i += 256) Sn[i] = ga.sn[m][i];
    Bp[t] = ga.bp[m][t];

    const int tn = t & 15;      // col group: cols tn*16 .. +15
    const int tm = t >> 4;      // token group: tokens tm*8 .. +7
    int bidx[4];
    #pragma unroll
    for (int j = 0; j < 4; j++){ int s = tn*4 + j; bidx[j] = s ^ ((s >> 3) & 7); }

    const int arow = t >> 1, akc = (t & 1) * 8;
    const float* aptr = x + (long)(n0 + arow) * DDIM + akc;
    const int bs = t & 63, bk0 = t >> 6;
    const int bphys = bs ^ ((bs >> 3) & 7);

    float acc[8][16];
    #pragma unroll
    for (int a = 0; a < 8; a++)
        #pragma unroll
        for (int i = 0; i < 16; i++) acc[a][i] = 0.f;

    for (int k0 = 0; k0 < DDIM; k0 += 16){
        __syncthreads();
        {   // A stage: 128 rows x 16 k, transposed scalar writes (2 lanes/bank)
            float4 a0 = *(const float4*)(aptr + k0);
            float4 a1 = *(const float4*)(aptr + k0 + 4);
            As[akc+0][arow] = a0.x; As[akc+1][arow] = a0.y;
            As[akc+2][arow] = a0.z; As[akc+3][arow] = a0.w;
            As[akc+4][arow] = a1.x; As[akc+5][arow] = a1.y;
            As[akc+6][arow] = a1.z; As[akc+7][arow] = a1.w;
        }
        #pragma unroll
        for (int i = 0; i < 4; i++){   // B stage: coalesced rows, swizzled slots
            int kk = bk0 + i*4;
            float4 bv = *(const float4*)(Wp + (long)(k0 + kk) * PROJ + bs*4);
            *(float4*)&Bs[kk][bphys*4] = bv;
        }
        __syncthreads();
        #pragma unroll
        for (int kk = 0; kk < 16; kk++){
            float4 a0 = *(const float4*)&As[kk][tm*8];
            float4 a1 = *(const float4*)&As[kk][tm*8+4];
            float a[8];
            a[0]=a0.x; a[1]=a0.y; a[2]=a0.z; a[3]=a0.w;
            a[4]=a1.x; a[5]=a1.y; a[6]=a1.z; a[7]=a1.w;
            #pragma unroll
            for (int j = 0; j < 4; j++){
                float4 b = *(const float4*)&Bs[kk][bidx[j]*4];
                #pragma unroll
                for (int ai = 0; ai < 8; ai++){
                    acc[ai][j*4+0] = fmaf(a[ai], b.x, acc[ai][j*4+0]);
                    acc[ai][j*4+1] = fmaf(a[ai], b.y, acc[ai][j*4+1]);
                    acc[ai][j*4+2] = fmaf(a[ai], b.z, acc[ai][j*4+2]);
                    acc[ai][j*4+3] = fmaf(a[ai], b.w, acc[ai][j*4+3]);
                }
            }
        }
    }

    // epilogue: bias + per-thread partial l2/dot sums over 16 cols x 8 tokens
    float ss[8];
    float dots[8][8];
    #pragma unroll
    for (int a = 0; a < 8; a++){
        ss[a] = 0.f;
        #pragma unroll
        for (int e = 0; e < 8; e++) dots[a][e] = 0.f;
    }
    #pragma unroll
    for (int j = 0; j < 4; j++)
        #pragma unroll
        for (int w = 0; w < 4; w++){
            int col = tn*16 + j*4 + w;
            float bias = Bp[col];
            float sn[8];
            *(float4*)(sn)   = *(const float4*)&Sn[col*8];
            *(float4*)(sn+4) = *(const float4*)&Sn[col*8+4];
            #pragma unroll
            for (int ai = 0; ai < 8; ai++){
                float pv = acc[ai][j*4+w] + bias;
                ss[ai] = fmaf(pv, pv, ss[ai]);
                #pragma unroll
                for (int e = 0; e < 8; e++) dots[ai][e] = fmaf(pv, sn[e], dots[ai][e]);
            }
        }
    #pragma unroll
    for (int o = 1; o <= 8; o <<= 1){
        #pragma unroll
        for (int ai = 0; ai < 8; ai++){
            ss[ai] += __shfl_xor(ss[ai], o, 64);
            #pragma unroll
            for (int e = 0; e < 8; e++) dots[ai][e] += __shfl_xor(dots[ai][e], o, 64);
        }
    }
    if (tn == 0){
        float scale = expf(fminf(ga.tp[m][0], LOG100));
        #pragma unroll
        for (int ai = 0; ai < 8; ai++){
            int n = n0 + tm*8 + ai;
            float inv = scale / (sqrtf(ss[ai]) + 1e-12f);
            float l[8], mx = -1e30f;
            #pragma unroll
            for (int e = 0; e < 8; e++){ l[e] = dots[ai][e] * inv; mx = fmaxf(mx, l[e]); }
            float g[8], s = 0.f;
            #pragma unroll
            for (int e = 0; e < 8; e++){ g[e] = expf(l[e] - mx); s += g[e]; }
            #pragma unroll
            for (int e = 0; e < 8; e++) g[e] /= s;
            int e0 = 0; float b0 = g[0];
            #pragma unroll
            for (int e = 1; e < 8; e++) if (g[e] > b0){ b0 = g[e]; e0 = e; }
            int e1 = (e0 == 0) ? 1 : 0; float b1v = g[e1];
            #pragma unroll
            for (int e = 0; e < 8; e++) if (e != e0 && g[e] > b1v){ b1v = g[e]; e1 = e; }
            float maskv = (m == 0) ? 1.f : ((label[n] == m - 1) ? 1.f : 0.f);
            float s2 = b0 + b1v + 1e-9f;
            long base = (long)m * NSLOT + 2*n;
            gw3[base]   = b0 / s2 * maskv;
            gw3[base+1] = b1v / s2 * maskv;
            idx3[base]   = e0;
            idx3[base+1] = e1;
        }
    }
}

// ---------- transposed-output bf16 MFMA GEMM core, 128x128, BK=32 ----------
template<int BFP32, int BGATHER, int OMODE>
__device__ __forceinline__
void gemm_core_t(short* As, short* Bs,
                 const unsigned short* __restrict__ AT, const void* __restrict__ Bv,
                 const float* __restrict__ bias, void* __restrict__ Cout,
                 int Kd, int Mld, int row0, int col0, int limitN,
                 const int* __restrict__ rowidx, const int* __restrict__ otok,
                 const float* __restrict__ gs)
{
    const int t = threadIdx.x;
    const int w = t >> 6, l = t & 63;
    const int qrow = l >> 2;
    const int kc = (l & 3) * 8;

    long arowg[2];
    #pragma unroll
    for (int q = 0; q < 2; q++)
        arowg[q] = (long)(row0 + w*32 + q*16 + qrow) * Kd;

    long browg[2];
    if (!BFP32){
        #pragma unroll
        for (int q = 0; q < 2; q++){
            int s = col0 + w*32 + q*16 + qrow;
            int gi = s;
            if (BGATHER) gi = (s < limitN) ? rowidx[s] : 0;
            browg[q] = (long)gi * Kd;
        }
    }
    const int sbr = t >> 1, sbc = (t & 1) * 16;
    long bbase_f = 0;
    if (BFP32){
        int s = col0 + sbr;
        int gi = s;
        if (BGATHER) gi = (s < limitN) ? rowidx[s] : 0;
        bbase_f = (long)gi * Kd;
    }

    const int wm = (w >> 1) * 64, wn = (w & 1) * 64;
    const int fr = l & 15, fk = l >> 4;
    const int koff = fk * 8, fk4 = fk * 4;

    f32x4 acc[4][4];
    #pragma unroll
    for (int i = 0; i < 4; i++)
        #pragma unroll
        for (int j = 0; j < 4; j++) acc[i][j] = (f32x4){0.f, 0.f, 0.f, 0.f};

    for (int k0 = 0; k0 < Kd; k0 += 32){
        __syncthreads();
        #pragma unroll
        for (int q = 0; q < 2; q++)
            gload16(AT + arowg[q] + k0 + kc, As + w*1024 + q*512);
        if (BFP32){
            const float* bp = (const float*)Bv + bbase_f + k0 + sbc;
            float4 f0 = *(const float4*)(bp);
            float4 f1 = *(const float4*)(bp + 4);
            float4 f2 = *(const float4*)(bp + 8);
            float4 f3 = *(const float4*)(bp + 12);
            short* dst = Bs + sbr*32 + sbc;
            *(short4v*)(dst+ 0) = (short4v){(short)f2bf(f0.x),(short)f2bf(f0.y),(short)f2bf(f0.z),(short)f2bf(f0.w)};
            *(short4v*)(dst+ 4) = (short4v){(short)f2bf(f1.x),(short)f2bf(f1.y),(short)f2bf(f1.z),(short)f2bf(f1.w)};
            *(short4v*)(dst+ 8) = (short4v){(short)f2bf(f2.x),(short)f2bf(f2.y),(short)f2bf(f2.z),(short)f2bf(f2.w)};
            *(short4v*)(dst+12) = (short4v){(short)f2bf(f3.x),(short)f2bf(f3.y),(short)f2bf(f3.z),(short)f2bf(f3.w)};
        } else {
            const unsigned short* bp = (const unsigned short*)Bv;
            #pragma unroll
            for (int q = 0; q < 2; q++)
                gload16(bp + browg[q] + k0 + kc, Bs + w*1024 + q*512);
        }
        __syncthreads();

        bf16x8 af[4], bfv[4];
        #pragma unroll
        for (int i = 0; i < 4; i++) af[i]  = *(const bf16x8*)&As[(wm + i*16 + fr)*32 + koff];
        #pragma unroll
        for (int j = 0; j < 4; j++) bfv[j] = *(const bf16x8*)&Bs[(wn + j*16 + fr)*32 + koff];
        #pragma unroll
        for (int i = 0; i < 4; i++)
            #pragma unroll
            for (int j = 0; j < 4; j++)
                acc[i][j] = __builtin_amdgcn_mfma_f32_16x16x32_bf16(af[i], bfv[j], acc[i][j], 0, 0, 0);
    }

    #pragma unroll
    for (int i = 0; i < 4; i++){
        const int mc = row0 + wm + i*16 + fk4;
        float4 bb = *(const float4*)(bias + mc);
        #pragma unroll
        for (int j = 0; j < 4; j++){
            int s = col0 + wn + j*16 + fr;
            if (s < limitN){
                if (OMODE == 1){
                    ushort4 u;
                    u.x = f2bf(fmaxf(acc[i][j][0] + bb.x, 0.f));
                    u.y = f2bf(fmaxf(acc[i][j][1] + bb.y, 0.f));
                    u.z = f2bf(fmaxf(acc[i][j][2] + bb.z, 0.f));
                    u.w = f2bf(fmaxf(acc[i][j][3] + bb.w, 0.f));
                    *(ushort4*)((unsigned short*)Cout + (long)s * Mld + mc) = u;
                } else {
                    int tk = otok[s];
                    float g = gs[s];
                    float* op = (float*)Cout + (long)tk * Mld + mc;
                    float4 c = *(const float4*)op;
                    c.x += g * (acc[i][j][0] + bb.x);
                    c.y += g * (acc[i][j][1] + bb.y);
                    c.z += g * (acc[i][j][2] + bb.z);
                    c.w += g * (acc[i][j][3] + bb.w);
                    *(float4*)op = c;
                }
            }
        }
    }
}

// ---------- y-GEMM core: 64 feat x 128 slots, BK=64 (two BK-32 sub-buffers) ----------
// As layout: [ks][64][32] shorts (4K shorts); Bs: [ks][128][32] (8K shorts)
__device__ __forceinline__
void gemm_core_y64(short* lds,
                   const unsigned short* __restrict__ AT, const unsigned short* __restrict__ Bv,
                   const float* __restrict__ bias, float* __restrict__ out,
                   int row0, int col0, int limitN,
                   const int* __restrict__ otok, const float* __restrict__ gs)
{
    short* As = lds;          // 4096 shorts
    short* Bs = lds + 4096;   // 8192 shorts
    const int t = threadIdx.x, w = t >> 6, l = t & 63;
    const int seg = (l & 3) * 8;     // 8-short (16B) segment within 32-k chunk

    const long arow = (long)(row0 + w*16 + (l >> 2)) * HDIM;
    long brow[2];
    #pragma unroll
    for (int hh = 0; hh < 2; hh++)
        brow[hh] = (long)(col0 + w*32 + hh*16 + (l >> 2)) * HDIM;

    const int wm = (w >> 1) * 32, wn = (w & 1) * 64;
    const int fr = l & 15, fk = l >> 4;
    const int koff = fk * 8, fk4 = fk * 4;

    f32x4 acc[2][4];
    #pragma unroll
    for (int i = 0; i < 2; i++)
        #pragma unroll
        for (int j = 0; j < 4; j++) acc[i][j] = (f32x4){0.f, 0.f, 0.f, 0.f};

    for (int k0 = 0; k0 < HDIM; k0 += 64){
        __syncthreads();
        #pragma unroll
        for (int ks = 0; ks < 2; ks++)
            gload16(AT + arow + k0 + ks*32 + seg, As + ks*2048 + w*512);
        #pragma unroll
        for (int ks = 0; ks < 2; ks++)
            #pragma unroll
            for (int hh = 0; hh < 2; hh++)
                gload16(Bv + brow[hh] + k0 + ks*32 + seg, Bs + ks*4096 + w*1024 + hh*512);
        __syncthreads();

        #pragma unroll
        for (int ks = 0; ks < 2; ks++){
            bf16x8 af[2], bfv[4];
            #pragma unroll
            for (int i = 0; i < 2; i++)
                af[i] = *(const bf16x8*)&As[ks*2048 + (wm + i*16 + fr)*32 + koff];
            #pragma unroll
            for (int j = 0; j < 4; j++)
                bfv[j] = *(const bf16x8*)&Bs[ks*4096 + (wn + j*16 + fr)*32 + koff];
            #pragma unroll
            for (int i = 0; i < 2; i++)
                #pragma unroll
                for (int j = 0; j < 4; j++)
                    acc[i][j] = __builtin_amdgcn_mfma_f32_16x16x32_bf16(af[i], bfv[j], acc[i][j], 0, 0, 0);
        }
    }

    #pragma unroll
    for (int i = 0; i < 2; i++){
        const int mc = row0 + wm + i*16 + fk4;
        float4 bb = *(const float4*)(bias + mc);
        #pragma unroll
        for (int j = 0; j < 4; j++){
            int s = col0 + wn + j*16 + fr;
            if (s < limitN){
                int tk = otok[s];
                float g = gs[s];
                float* op = out + (long)tk * DDIM + mc;
                float4 c = *(const float4*)op;
                c.x += g * (acc[i][j][0] + bb.x);
                c.y += g * (acc[i][j][1] + bb.y);
                c.z += g * (acc[i][j][2] + bb.z);
                c.w += g * (acc[i][j][3] + bb.w);
                *(float4*)op = c;
            }
        }
    }
}

template<int BFP32, int BGATHER, int OMODE>
__global__ __launch_bounds__(256)
void mgemm3_k(const unsigned short* __restrict__ AT, const void* __restrict__ Bv,
              const float* __restrict__ bias, void* __restrict__ Cout,
              int Kd, int Mld,
              const int* __restrict__ rowidx, const int* __restrict__ otok,
              const float* __restrict__ gs, const int* __restrict__ cntp, int cnti)
{
    __shared__ __align__(16) short As[128*32];
    __shared__ __align__(16) short Bs[128*32];
    int limit = cntp[cnti]; if (limit > CAP) limit = CAP;
    int row0 = blockIdx.x * 128, col0 = blockIdx.y * 128;
    if (col0 >= limit) return;
    gemm_core_t<BFP32, BGATHER, OMODE>(As, Bs, AT, Bv, bias, Cout, Kd, Mld,
                                       row0, col0, limit, rowidx, otok, gs);
}

// ---------- balanced dual-role FFN: bx = slot block (XCD-local), by = role ----------
// by 0..7:  h-GEMM(eh), 128 feat cols each, BK=32, 16 steps
// by 8..15: y-GEMM(eh-1), 64 feat cols each, BK=64, 16 steps
template<int BFP32>
__global__ __launch_bounds__(256)
void ffn3_k(const void* __restrict__ xsrc,
            const unsigned short* __restrict__ W1T, const float* __restrict__ b1,
            const unsigned short* __restrict__ W2T, const float* __restrict__ b2,
            unsigned short* __restrict__ h0, unsigned short* __restrict__ h1,
            float* __restrict__ out,
            const int* __restrict__ tok, const float* __restrict__ gslot,
            const int* __restrict__ cntk, int eh)
{
    __shared__ __align__(16) short lds[12288];   // 24KB
    const int bx = blockIdx.x, by = blockIdx.y;
    const int col0 = bx * 128;                   // slots
    if (by < 8){
        if (eh > 7) return;
        int limit = cntk[eh]; if (limit > CAP) limit = CAP;
        if (col0 >= limit) return;
        unsigned short* hd = (eh & 1) ? h1 : h0;
        gemm_core_t<BFP32, 1, 1>(lds, lds + 4096,
                                 W1T + (size_t)eh*HDIM*DDIM, xsrc, b1 + (size_t)eh*HDIM,
                                 hd, DDIM, HDIM, by*128, col0, limit,
                                 tok + (size_t)eh*CAP, nullptr, nullptr);
    } else {
        int ey = eh - 1; if (ey < 0) return;
        int limit = cntk[ey]; if (limit > CAP) limit = CAP;
        if (col0 >= limit) return;
        const unsigned short* hs = (ey & 1) ? h1 : h0;
        gemm_core_y64(lds, W2T + (size_t)ey*DDIM*HDIM, hs, b2 + (size_t)ey*DDIM,
                      out, (by-8)*64, col0, limit,
                      tok + (size_t)ey*CAP, gslot + (size_t)ey*CAP);
    }
}

// ---------- ranking ----------
__global__ __launch_bounds__(1024)
void rank_count_k(const int* __restrict__ idx, const int* __restrict__ label, int mode,
                  int* __restrict__ bcnt)
{
    __shared__ int c[NEXP];
    int t = threadIdx.x;
    if (t < NEXP) c[t] = 0;
    __syncthreads();
    int s = blockIdx.x * 1024 + t;
    int n = s >> 1;
    int e = idx[s];
    bool valid = (mode == 0) || (label[n] == mode - 1);
    if (valid) atomicAdd(&c[e], 1);
    __syncthreads();
    if (t < NEXP) bcnt[blockIdx.x * NEXP + t] = c[t];
}

__global__ void rank_scan_k(const int* __restrict__ bcnt, int* __restrict__ boff,
                            int* __restrict__ cntk)
{
    int e = threadIdx.x;
    if (e < NEXP){
        int run = 0;
        for (int b = 0; b < NSLOT/1024; b++){
            boff[b * NEXP + e] = run;
            run += bcnt[b * NEXP + e];
        }
        cntk[e] = run < CAP ? run : CAP;
    }
}

__global__ __launch_bounds__(1024)
void rank_assign_k(const int* __restrict__ idx, const int* __restrict__ label, int mode,
                   const int* __restrict__ boff, const float* __restrict__ gw,
                   const float* __restrict__ dscale, int use_scale,
                   int* __restrict__ tok_of, float* __restrict__ gs_of)
{
    __shared__ int wcnt[16][NEXP];
    __shared__ int woff[16][NEXP];
    int t = threadIdx.x;
    int s = blockIdx.x * 1024 + t;
    int n = s >> 1;
    int e = idx[s];
    bool valid = (mode == 0) || (label[n] == mode - 1);
    int w = t >> 6, lane = t & 63;
    unsigned long long lt = (lane == 0) ? 0ull : ((1ull << lane) - 1ull);
    int myrank = 0;
    #pragma unroll
    for (int ei = 0; ei < NEXP; ei++){
        unsigned long long bal = __ballot(valid && (e == ei));
        if (ei == e) myrank = __popcll(bal & lt);
        if (lane == 0) wcnt[w][ei] = __popcll(bal);
    }
    __syncthreads();
    if (t < NEXP){
        int run = boff[blockIdx.x * NEXP + t];
        for (int w2 = 0; w2 < 16; w2++){
            woff[w2][t] = run;
            run += wcnt[w2][t];
        }
    }
    __syncthreads();
    int pos = woff[w][e] + myrank;
    bool keep = valid && (pos < CAP);
    if (keep){
        float scale = use_scale ? dscale[0] : 1.f;
        tok_of[e * CAP + pos] = n;
        gs_of[e * CAP + pos] = gw[s] * scale;
    }
}

extern "C" void kernel_launch(void* const* d_in, const int* in_sizes, int n_in,
                              void* d_out, int out_size, void* d_ws, size_t ws_size,
                              hipStream_t stream)
{
    (void)in_sizes; (void)n_in; (void)out_size;
    const float* x      = (const float*)d_in[0];
    const int*   label  = (const int*)  d_in[1];
    const float* dscale = (const float*)d_in[2];
    float* out = (float*)d_out;

    const size_t HS   = (size_t)CAP * HDIM * 2;             // 32MB per h slot
    const size_t WT2  = (size_t)2 * NEXP * DDIM * HDIM * 2; // 16MB
    const size_t XB   = (size_t)NTOK * DDIM * 2;            // 64MB
    const size_t SMALL = (size_t)3*PROJ*NEXP*4 + (size_t)3*NSLOT*4*2 +
                         (size_t)NEXP*CAP*4*2 + (size_t)(NSLOT/1024)*NEXP*4*2 + 256;
    const size_t base = HS + WT2 + SMALL;

    bool pip = false, useXb = false;
    if      (ws_size >= base + HS + XB){ pip = true; useXb = true; }
    else if (ws_size >= base + XB)     { useXb = true; }
    else if (ws_size >= base + HS)     { pip = true; }
    else if (ws_size < base) return;   // clean failure, not a fault

    char* p = (char*)d_ws;
    unsigned short* h0  = (unsigned short*)p; p += HS;
    unsigned short* W1T = (unsigned short*)p; p += WT2/2;
    unsigned short* W2T = (unsigned short*)p; p += WT2/2;
    float* simn3 = (float*)p;  p += (size_t)3*PROJ*NEXP*4;
    int*   idx3  = (int*)p;    p += (size_t)3*NSLOT*4;
    float* gw3   = (float*)p;  p += (size_t)3*NSLOT*4;
    int*   tok   = (int*)p;    p += (size_t)NEXP*CAP*4;
    float* gslot = (float*)p;  p += (size_t)NEXP*CAP*4;
    int*   bcnt  = (int*)p;    p += (size_t)(NSLOT/1024)*NEXP*4;
    int*   boff  = (int*)p;    p += (size_t)(NSLOT/1024)*NEXP*4;
    int*   cntk  = (int*)p;    p += 256;
    unsigned short* h1 = nullptr;
    unsigned short* xb = nullptr;
    if (pip){ h1 = (unsigned short*)p; p += HS; }
    if (useXb){ xb = (unsigned short*)p; }

    zero_k<<<dim3((NTOK*DDIM/4)/256), dim3(256), 0, stream>>>((float4*)out);
    if (useXb)
        cvt_k<<<dim3(NTOK*DDIM/4/256), dim3(256), 0, stream>>>((const float4*)x, (ushort4*)xb, NTOK*DDIM/4);

    GateArgs ga; SimArgs sa;
    for (int m = 0; m < 3; m++){
        ga.Wp[m] = (const float*)d_in[3 + 8*m + 0];
        ga.bp[m] = (const float*)d_in[3 + 8*m + 1];
        ga.sn[m] = simn3 + (size_t)m * PROJ * NEXP;
        ga.tp[m] = (const float*)d_in[3 + 8*m + 3];
        sa.sim[m] = (const float*)d_in[3 + 8*m + 2];
    }
    simn3_k<<<dim3(3), dim3(256), 0, stream>>>(sa, simn3);
    pgate4_k<<<dim3(NTOK/128, 3), dim3(256), 0, stream>>>(x, label, ga, idx3, gw3);

    for (int m = 0; m < 3; m++){
        const float* W1 = (const float*)d_in[3 + 8*m + 4];
        const float* b1 = (const float*)d_in[3 + 8*m + 5];
        const float* W2 = (const float*)d_in[3 + 8*m + 6];
        const float* b2 = (const float*)d_in[3 + 8*m + 7];
        const int* idxm = idx3 + (size_t)m * NSLOT;
        const float* gwm = gw3 + (size_t)m * NSLOT;

        trans2_k<<<dim3(32, 32, 16), dim3(32,8), 0, stream>>>(W1, W2, W1T, W2T);

        rank_count_k<<<dim3(NSLOT/1024), dim3(1024), 0, stream>>>(idxm, label, m, bcnt);
        rank_scan_k<<<dim3(1), dim3(64), 0, stream>>>(bcnt, boff, cntk);
        rank_assign_k<<<dim3(NSLOT/1024), dim3(1024), 0, stream>>>(
            idxm, label, m, boff, gwm, dscale, (m > 0) ? 1 : 0, tok, gslot);

        if (pip){
            for (int eh = 0; eh <= 8; eh++){
                if (useXb)
                    ffn3_k<0><<<dim3(128, 16), 256, 0, stream>>>(
                        xb, W1T, b1, W2T, b2, h0, h1, out, tok, gslot, cntk, eh);
                else
                    ffn3_k<1><<<dim3(128, 16), 256, 0, stream>>>(
                        x, W1T, b1, W2T, b2, h0, h1, out, tok, gslot, cntk, eh);
            }
        } else {
            for (int e = 0; e < NEXP; e++){
                if (useXb)
                    mgemm3_k<0, 1, 1><<<dim3(HDIM/128, CAP/128), 256, 0, stream>>>(
                        W1T + (size_t)e*HDIM*DDIM, xb, b1 + (size_t)e*HDIM, h0,
                        DDIM, HDIM, tok + (size_t)e*CAP, nullptr, nullptr, cntk, e);
                else
                    mgemm3_k<1, 1, 1><<<dim3(HDIM/128, CAP/128), 256, 0, stream>>>(
                        W1T + (size_t)e*HDIM*DDIM, x, b1 + (size_t)e*HDIM, h0,
                        DDIM, HDIM, tok + (size_t)e*CAP, nullptr, nullptr, cntk, e);
                mgemm3_k<0, 0, 3><<<dim3(DDIM/128, CAP/128), 256, 0, stream>>>(
                    W2T + (size_t)e*DDIM*HDIM, h0, b2 + (size_t)e*DDIM, out,
                    HDIM, DDIM, nullptr, tok + (size_t)e*CAP, gslot + (size_t)e*CAP, cntk, e);
            }
        }
    }
}

// Round 8
// 1844.777 us; speedup vs baseline: 1.3361x; 1.2745x over previous
//
#include <hip/hip_runtime.h>

#define NTOK 65536
#define DDIM 512
#define HDIM 1024
#define NEXP 8
#define PROJ 256
#define CAP  16384
#define NSLOT (2*NTOK)
#define LOG100 4.605170185988091f

typedef __attribute__((ext_vector_type(8))) short bf16x8;
typedef __attribute__((ext_vector_type(4))) short short4v;
typedef __attribute__((ext_vector_type(4))) float f32x4;

// ---------- helpers ----------
__device__ inline float bf2f(unsigned short u){
    union { float f; unsigned int i; } c; c.i = ((unsigned int)u) << 16; return c.f;
}
__device__ inline unsigned short f2bf(float f){
    union { float f; unsigned int i; } c; c.f = f;
    unsigned int x = c.i;
    return (unsigned short)((x + 0x7fffu + ((x >> 16) & 1u)) >> 16); // RTNE
}
__device__ inline void gload16(const void* g, void* lds){
    __builtin_amdgcn_global_load_lds(
        (const __attribute__((address_space(1))) unsigned int*)g,
        (__attribute__((address_space(3))) unsigned int*)lds, 16, 0, 0);
}

__global__ void zero_k(float4* __restrict__ p){
    p[(long)blockIdx.x * 256 + threadIdx.x] = float4{0.f, 0.f, 0.f, 0.f};
}

__global__ void cvt_k(const float4* __restrict__ src, ushort4* __restrict__ dst, int n4){
    int i = blockIdx.x * 256 + threadIdx.x;
    if (i < n4){
        float4 f = src[i];
        ushort4 u; u.x = f2bf(f.x); u.y = f2bf(f.y); u.z = f2bf(f.z); u.w = f2bf(f.w);
        dst[i] = u;
    }
}

// ---------- generic 32x32-tiled transpose+convert body ----------
__device__ inline void trans_body(const float* in, unsigned short* out, int R, int C){
    int rbase = blockIdx.y * 32, cbase = blockIdx.x * 32;
    if (rbase >= R || cbase >= C) return;
    __shared__ float tile[32][33];
    int tx = threadIdx.x, ty = threadIdx.y;   // (32,8)
    #pragma unroll
    for (int i = 0; i < 4; i++)
        tile[ty + i*8][tx] = in[(long)(rbase + ty + i*8) * C + cbase + tx];
    __syncthreads();
    #pragma unroll
    for (int i = 0; i < 4; i++)
        out[(long)(cbase + ty + i*8) * R + rbase + tx] = f2bf(tile[tx][ty + i*8]);
}

// per-model W1/W2 transpose (Tier B/C): z<8 W1 expert z, z>=8 W2 expert z-8
__global__ __launch_bounds__(256)
void trans2_k(const float* __restrict__ W1, const float* __restrict__ W2,
              unsigned short* __restrict__ W1T, unsigned short* __restrict__ W2T)
{
    int z = blockIdx.z;
    if (z < 8) trans_body(W1 + (size_t)z*DDIM*HDIM, W1T + (size_t)z*DDIM*HDIM, DDIM, HDIM);
    else       trans_body(W2 + (size_t)(z-8)*DDIM*HDIM, W2T + (size_t)(z-8)*DDIM*HDIM, HDIM, DDIM);
}

// all-model W1/W2 transpose (Tier A): z = m*16 + piece
struct W12P { const float* W1[3]; const float* W2[3]; };
__global__ __launch_bounds__(256)
void transW12all_k(W12P wp, unsigned short* __restrict__ W1T3, unsigned short* __restrict__ W2T3)
{
    int z = blockIdx.z, m = z >> 4, piece = z & 15;
    if (piece < 8)
        trans_body(wp.W1[m] + (size_t)piece*DDIM*HDIM,
                   W1T3 + ((size_t)m*8 + piece)*DDIM*HDIM, DDIM, HDIM);
    else
        trans_body(wp.W2[m] + (size_t)(piece-8)*DDIM*HDIM,
                   W2T3 + ((size_t)m*8 + piece-8)*DDIM*HDIM, HDIM, DDIM);
}

// Wp transpose: [512][256] f32 -> [256][512] bf16, per model
struct TpArgs { const float* Wp[3]; };
__global__ __launch_bounds__(256)
void transWp_k(TpArgs ta, unsigned short* __restrict__ WpT3)
{
    int m = blockIdx.z;
    trans_body(ta.Wp[m], WpT3 + (size_t)m*PROJ*DDIM, DDIM, PROJ);
}

// ---------- normalize sim columns ----------
struct SimArgs { const float* sim[3]; };
__global__ void simn3_k(SimArgs sa, float* __restrict__ simn3){
    __shared__ float red[256];
    const float* sim = sa.sim[blockIdx.x];
    float* simn = simn3 + (size_t)blockIdx.x * PROJ * NEXP;
    int j = threadIdx.x;
    for (int e = 0; e < NEXP; e++){
        float v = sim[j*NEXP + e];
        red[j] = v*v;
        __syncthreads();
        for (int s = 128; s > 0; s >>= 1){
            if (j < s) red[j] += red[j + s];
            __syncthreads();
        }
        float nrm = sqrtf(red[0]) + 1e-12f;
        __syncthreads();
        simn[j*NEXP + e] = v / nrm;
    }
}

// ---------- W' = Wp @ simn (fp32), bd = bp @ simn ----------
struct WprodArgs { const float* Wp[3]; const float* bp[3]; };
__global__ __launch_bounds__(256)
void wprod_k(WprodArgs wa, const float* __restrict__ simn3,
             float* __restrict__ Wn3, float* __restrict__ bd3)
{
    int m = blockIdx.x;
    __shared__ float Sn[PROJ*NEXP];
    const float* Wp = wa.Wp[m];
    int t = threadIdx.x;
    for (int i = t; i < PROJ*NEXP; i += 256) Sn[i] = simn3[(size_t)m*PROJ*NEXP + i];
    __syncthreads();
    for (int r = t; r < DDIM; r += 256){
        float d[8];
        #pragma unroll
        for (int e = 0; e < 8; e++) d[e] = 0.f;
        for (int p = 0; p < PROJ; p++){
            float w = Wp[(size_t)r*PROJ + p];
            #pragma unroll
            for (int e = 0; e < 8; e++) d[e] = fmaf(w, Sn[p*8+e], d[e]);
        }
        #pragma unroll
        for (int e = 0; e < 8; e++) Wn3[((size_t)m*DDIM + r)*8 + e] = d[e];
    }
    if (t < 8){
        float s = 0.f;
        for (int p = 0; p < PROJ; p++) s = fmaf(wa.bp[m][p], Sn[p*8+t], s);
        bd3[m*8 + t] = s;
    }
}

// ---------- pss: MFMA P-GEMM, epilogue = row-norm^2 only (no P store) ----------
// grid (2 feat-blocks, 512 token-blocks, 3 models). ssbuf [2][3][NTOK].
struct PssArgs { const float* bp[3]; };
__global__ __launch_bounds__(256)
void pss_k(const unsigned short* __restrict__ WpT3, const unsigned short* __restrict__ xb,
           PssArgs pa, float* __restrict__ ssbuf)
{
    __shared__ __align__(16) short As[128*32];
    __shared__ __align__(16) short Bs[128*32];
    __shared__ float ssl[2][128];
    const int m = blockIdx.z;
    const int row0 = blockIdx.x * 128;   // feat block
    const int n0 = blockIdx.y * 128;     // token block
    const unsigned short* AT = WpT3 + (size_t)m * PROJ * DDIM;
    const float* bp = pa.bp[m];

    const int t = threadIdx.x, w = t >> 6, l = t & 63;
    const int qrow = l >> 2, kc = (l & 3) * 8;
    long arowg[2], browg[2];
    #pragma unroll
    for (int q = 0; q < 2; q++){
        arowg[q] = (long)(row0 + w*32 + q*16 + qrow) * DDIM;
        browg[q] = (long)(n0   + w*32 + q*16 + qrow) * DDIM;
    }
    const int wm = (w >> 1) * 64, wn = (w & 1) * 64;
    const int fr = l & 15, fk = l >> 4;
    const int koff = fk * 8, fk4 = fk * 4;

    f32x4 acc[4][4];
    #pragma unroll
    for (int i = 0; i < 4; i++)
        #pragma unroll
        for (int j = 0; j < 4; j++) acc[i][j] = (f32x4){0.f, 0.f, 0.f, 0.f};

    for (int k0 = 0; k0 < DDIM; k0 += 32){
        __syncthreads();
        #pragma unroll
        for (int q = 0; q < 2; q++) gload16(AT + arowg[q] + k0 + kc, As + w*1024 + q*512);
        #pragma unroll
        for (int q = 0; q < 2; q++) gload16(xb + browg[q] + k0 + kc, Bs + w*1024 + q*512);
        __syncthreads();
        bf16x8 af[4], bfv[4];
        #pragma unroll
        for (int i = 0; i < 4; i++) af[i]  = *(const bf16x8*)&As[(wm + i*16 + fr)*32 + koff];
        #pragma unroll
        for (int j = 0; j < 4; j++) bfv[j] = *(const bf16x8*)&Bs[(wn + j*16 + fr)*32 + koff];
        #pragma unroll
        for (int i = 0; i < 4; i++)
            #pragma unroll
            for (int j = 0; j < 4; j++)
                acc[i][j] = __builtin_amdgcn_mfma_f32_16x16x32_bf16(af[i], bfv[j], acc[i][j], 0, 0, 0);
    }

    // ss partial: sum over this thread's 16 feats per token, reduce over fk lanes
    float part[4];
    #pragma unroll
    for (int j = 0; j < 4; j++){
        float s = 0.f;
        #pragma unroll
        for (int i = 0; i < 4; i++){
            int mc = row0 + wm + i*16 + fk4;
            float4 bb = *(const float4*)(bp + mc);
            float v0 = acc[i][j][0] + bb.x;
            float v1 = acc[i][j][1] + bb.y;
            float v2 = acc[i][j][2] + bb.z;
            float v3 = acc[i][j][3] + bb.w;
            s += v0*v0 + v1*v1 + v2*v2 + v3*v3;
        }
        s += __shfl_xor(s, 16, 64);
        s += __shfl_xor(s, 32, 64);
        part[j] = s;
    }
    if (fk == 0){
        #pragma unroll
        for (int j = 0; j < 4; j++) ssl[w >> 1][wn + j*16 + fr] = part[j];
    }
    __syncthreads();
    if (t < 128)
        ssbuf[((size_t)blockIdx.x*3 + m)*NTOK + n0 + t] = ssl[0][t] + ssl[1][t];
}

// ---------- gatefin: thin fp32 dots GEMM + softmax + top2 ----------
struct GfArgs { const float* tp[3]; };
__global__ __launch_bounds__(256)
void gatefin_k(const float* __restrict__ x, const int* __restrict__ label,
               const float* __restrict__ Wn3, const float* __restrict__ bd3,
               const float* __restrict__ ssbuf, GfArgs gf,
               int* __restrict__ idx3, float* __restrict__ gw3)
{
    __shared__ float As[256][17];
    const int t = threadIdx.x;
    const int n = blockIdx.x * 256 + t;
    float dots[3][8];
    #pragma unroll
    for (int m = 0; m < 3; m++)
        #pragma unroll
        for (int e = 0; e < 8; e++) dots[m][e] = 0.f;

    for (int k0 = 0; k0 < DDIM; k0 += 16){
        __syncthreads();
        {
            const float4* src = (const float4*)(x + (size_t)n * DDIM + k0);
            float4 v0 = src[0], v1 = src[1], v2 = src[2], v3 = src[3];
            float* d = &As[t][0];
            d[0]=v0.x; d[1]=v0.y; d[2]=v0.z; d[3]=v0.w;
            d[4]=v1.x; d[5]=v1.y; d[6]=v1.z; d[7]=v1.w;
            d[8]=v2.x; d[9]=v2.y; d[10]=v2.z; d[11]=v2.w;
            d[12]=v3.x; d[13]=v3.y; d[14]=v3.z; d[15]=v3.w;
        }
        __syncthreads();
        for (int kk = 0; kk < 16; kk++){
            float a = As[t][kk];
            #pragma unroll
            for (int m = 0; m < 3; m++){
                const float* wr = Wn3 + ((size_t)m*DDIM + k0 + kk)*8;  // uniform -> s_load
                #pragma unroll
                for (int e = 0; e < 8; e++) dots[m][e] = fmaf(a, wr[e], dots[m][e]);
            }
        }
    }

    int lab = label[n];
    #pragma unroll
    for (int m = 0; m < 3; m++){
        float ss = ssbuf[(0*3+m)*(size_t)NTOK + n] + ssbuf[(1*3+m)*(size_t)NTOK + n];
        float scale = expf(fminf(gf.tp[m][0], LOG100));
        float inv = scale / (sqrtf(ss) + 1e-12f);
        float l8[8], mx = -1e30f;
        #pragma unroll
        for (int e = 0; e < 8; e++){ l8[e] = (dots[m][e] + bd3[m*8+e]) * inv; mx = fmaxf(mx, l8[e]); }
        float g[8], s = 0.f;
        #pragma unroll
        for (int e = 0; e < 8; e++){ g[e] = expf(l8[e] - mx); s += g[e]; }
        #pragma unroll
        for (int e = 0; e < 8; e++) g[e] /= s;
        int e0 = 0; float b0 = g[0];
        #pragma unroll
        for (int e = 1; e < 8; e++) if (g[e] > b0){ b0 = g[e]; e0 = e; }
        int e1 = (e0 == 0) ? 1 : 0; float b1v = g[e1];
        #pragma unroll
        for (int e = 0; e < 8; e++) if (e != e0 && g[e] > b1v){ b1v = g[e]; e1 = e; }
        float maskv = (m == 0) ? 1.f : ((lab == m - 1) ? 1.f : 0.f);
        float s2 = b0 + b1v + 1e-9f;
        size_t base = (size_t)m * NSLOT + 2*(size_t)n;
        gw3[base]   = b0 / s2 * maskv;
        gw3[base+1] = b1v / s2 * maskv;
        idx3[base]   = e0;
        idx3[base+1] = e1;
    }
}

// ---------- transposed-output bf16 MFMA GEMM core, 128x128, BK=32 ----------
template<int BGATHER, int OMODE>
__device__ __forceinline__
void gemm_core_t(short* As, short* Bs,
                 const unsigned short* __restrict__ AT, const unsigned short* __restrict__ Bv,
                 const float* __restrict__ bias, void* __restrict__ Cout,
                 int Kd, int Mld, int row0, int col0, int limitN,
                 const int* __restrict__ rowidx, const int* __restrict__ otok,
                 const float* __restrict__ gs)
{
    const int t = threadIdx.x;
    const int w = t >> 6, l = t & 63;
    const int qrow = l >> 2;
    const int kc = (l & 3) * 8;

    long arowg[2], browg[2];
    #pragma unroll
    for (int q = 0; q < 2; q++){
        arowg[q] = (long)(row0 + w*32 + q*16 + qrow) * Kd;
        int s = col0 + w*32 + q*16 + qrow;
        int gi = s;
        if (BGATHER) gi = (s < limitN) ? rowidx[s] : 0;
        browg[q] = (long)gi * Kd;
    }

    const int wm = (w >> 1) * 64, wn = (w & 1) * 64;
    const int fr = l & 15, fk = l >> 4;
    const int koff = fk * 8, fk4 = fk * 4;

    f32x4 acc[4][4];
    #pragma unroll
    for (int i = 0; i < 4; i++)
        #pragma unroll
        for (int j = 0; j < 4; j++) acc[i][j] = (f32x4){0.f, 0.f, 0.f, 0.f};

    for (int k0 = 0; k0 < Kd; k0 += 32){
        __syncthreads();
        #pragma unroll
        for (int q = 0; q < 2; q++) gload16(AT + arowg[q] + k0 + kc, As + w*1024 + q*512);
        #pragma unroll
        for (int q = 0; q < 2; q++) gload16(Bv + browg[q] + k0 + kc, Bs + w*1024 + q*512);
        __syncthreads();
        bf16x8 af[4], bfv[4];
        #pragma unroll
        for (int i = 0; i < 4; i++) af[i]  = *(const bf16x8*)&As[(wm + i*16 + fr)*32 + koff];
        #pragma unroll
        for (int j = 0; j < 4; j++) bfv[j] = *(const bf16x8*)&Bs[(wn + j*16 + fr)*32 + koff];
        #pragma unroll
        for (int i = 0; i < 4; i++)
            #pragma unroll
            for (int j = 0; j < 4; j++)
                acc[i][j] = __builtin_amdgcn_mfma_f32_16x16x32_bf16(af[i], bfv[j], acc[i][j], 0, 0, 0);
    }

    #pragma unroll
    for (int i = 0; i < 4; i++){
        const int mc = row0 + wm + i*16 + fk4;
        float4 bb = *(const float4*)(bias + mc);
        #pragma unroll
        for (int j = 0; j < 4; j++){
            int s = col0 + wn + j*16 + fr;
            if (s < limitN){
                if (OMODE == 1){
                    ushort4 u;
                    u.x = f2bf(fmaxf(acc[i][j][0] + bb.x, 0.f));
                    u.y = f2bf(fmaxf(acc[i][j][1] + bb.y, 0.f));
                    u.z = f2bf(fmaxf(acc[i][j][2] + bb.z, 0.f));
                    u.w = f2bf(fmaxf(acc[i][j][3] + bb.w, 0.f));
                    *(ushort4*)((unsigned short*)Cout + (long)s * Mld + mc) = u;
                } else {
                    int tk = otok[s];
                    float g = gs[s];
                    float* op = (float*)Cout + (long)tk * Mld + mc;
                    float4 c = *(const float4*)op;
                    c.x += g * (acc[i][j][0] + bb.x);
                    c.y += g * (acc[i][j][1] + bb.y);
                    c.z += g * (acc[i][j][2] + bb.z);
                    c.w += g * (acc[i][j][3] + bb.w);
                    *(float4*)op = c;
                }
            }
        }
    }
}

// ---------- y-GEMM core: 64 feat x 128 slots, BK=64 ----------
__device__ __forceinline__
void gemm_core_y64(short* lds,
                   const unsigned short* __restrict__ AT, const unsigned short* __restrict__ Bv,
                   const float* __restrict__ bias, float* __restrict__ out,
                   int row0, int col0, int limitN,
                   const int* __restrict__ otok, const float* __restrict__ gs)
{
    short* As = lds;
    short* Bs = lds + 4096;
    const int t = threadIdx.x, w = t >> 6, l = t & 63;
    const int seg = (l & 3) * 8;

    const long arow = (long)(row0 + w*16 + (l >> 2)) * HDIM;
    long brow[2];
    #pragma unroll
    for (int hh = 0; hh < 2; hh++)
        brow[hh] = (long)(col0 + w*32 + hh*16 + (l >> 2)) * HDIM;

    const int wm = (w >> 1) * 32, wn = (w & 1) * 64;
    const int fr = l & 15, fk = l >> 4;
    const int koff = fk * 8, fk4 = fk * 4;

    f32x4 acc[2][4];
    #pragma unroll
    for (int i = 0; i < 2; i++)
        #pragma unroll
        for (int j = 0; j < 4; j++) acc[i][j] = (f32x4){0.f, 0.f, 0.f, 0.f};

    for (int k0 = 0; k0 < HDIM; k0 += 64){
        __syncthreads();
        #pragma unroll
        for (int ks = 0; ks < 2; ks++)
            gload16(AT + arow + k0 + ks*32 + seg, As + ks*2048 + w*512);
        #pragma unroll
        for (int ks = 0; ks < 2; ks++)
            #pragma unroll
            for (int hh = 0; hh < 2; hh++)
                gload16(Bv + brow[hh] + k0 + ks*32 + seg, Bs + ks*4096 + w*1024 + hh*512);
        __syncthreads();
        #pragma unroll
        for (int ks = 0; ks < 2; ks++){
            bf16x8 af[2], bfv[4];
            #pragma unroll
            for (int i = 0; i < 2; i++)
                af[i] = *(const bf16x8*)&As[ks*2048 + (wm + i*16 + fr)*32 + koff];
            #pragma unroll
            for (int j = 0; j < 4; j++)
                bfv[j] = *(const bf16x8*)&Bs[ks*4096 + (wn + j*16 + fr)*32 + koff];
            #pragma unroll
            for (int i = 0; i < 2; i++)
                #pragma unroll
                for (int j = 0; j < 4; j++)
                    acc[i][j] = __builtin_amdgcn_mfma_f32_16x16x32_bf16(af[i], bfv[j], acc[i][j], 0, 0, 0);
        }
    }

    #pragma unroll
    for (int i = 0; i < 2; i++){
        const int mc = row0 + wm + i*16 + fk4;
        float4 bb = *(const float4*)(bias + mc);
        #pragma unroll
        for (int j = 0; j < 4; j++){
            int s = col0 + wn + j*16 + fr;
            if (s < limitN){
                int tk = otok[s];
                float g = gs[s];
                float* op = out + (long)tk * DDIM + mc;
                float4 c = *(const float4*)op;
                c.x += g * (acc[i][j][0] + bb.x);
                c.y += g * (acc[i][j][1] + bb.y);
                c.z += g * (acc[i][j][2] + bb.z);
                c.w += g * (acc[i][j][3] + bb.w);
                *(float4*)op = c;
            }
        }
    }
}

// ---------- serial GEMM (Tier C) ----------
template<int BGATHER, int OMODE>
__global__ __launch_bounds__(256)
void mgemm3_k(const unsigned short* __restrict__ AT, const unsigned short* __restrict__ Bv,
              const float* __restrict__ bias, void* __restrict__ Cout,
              int Kd, int Mld,
              const int* __restrict__ rowidx, const int* __restrict__ otok,
              const float* __restrict__ gs, const int* __restrict__ cntp, int cnti)
{
    __shared__ __align__(16) short As[128*32];
    __shared__ __align__(16) short Bs[128*32];
    int limit = cntp[cnti]; if (limit > CAP) limit = CAP;
    int row0 = blockIdx.x * 128, col0 = blockIdx.y * 128;
    if (col0 >= limit) return;
    gemm_core_t<BGATHER, OMODE>(As, Bs, AT, Bv, bias, Cout, Kd, Mld,
                                row0, col0, limit, rowidx, otok, gs);
}

// ---------- cross-model pipelined FFN (Tier A): ge = global expert step ----------
struct FfnP { const float* b1[3]; const float* b2[3]; };
__global__ __launch_bounds__(256)
void ffnA_k(const unsigned short* __restrict__ xb,
            const unsigned short* __restrict__ W1T3, const unsigned short* __restrict__ W2T3,
            FfnP fp, unsigned short* __restrict__ h0, unsigned short* __restrict__ h1,
            float* __restrict__ out,
            const int* __restrict__ tok3, const float* __restrict__ gslot3,
            const int* __restrict__ cntk3, int ge)
{
    __shared__ __align__(16) short lds[12288];
    const int bx = blockIdx.x, by = blockIdx.y;
    const int col0 = bx * 128;
    if (by < 8){
        if (ge >= 24) return;
        int m = ge >> 3, e = ge & 7;
        int limit = cntk3[m*16 + e]; if (limit > CAP) limit = CAP;
        if (col0 >= limit) return;
        unsigned short* hd = (ge & 1) ? h1 : h0;
        gemm_core_t<1, 1>(lds, lds + 4096,
                          W1T3 + ((size_t)(m*8+e))*HDIM*DDIM, xb, fp.b1[m] + (size_t)e*HDIM,
                          hd, DDIM, HDIM, by*128, col0, limit,
                          tok3 + ((size_t)m*NEXP + e)*CAP, nullptr, nullptr);
    } else {
        int gy = ge - 1; if (gy < 0) return;
        int m = gy >> 3, e = gy & 7;
        int limit = cntk3[m*16 + e]; if (limit > CAP) limit = CAP;
        if (col0 >= limit) return;
        const unsigned short* hs = (gy & 1) ? h1 : h0;
        gemm_core_y64(lds, W2T3 + ((size_t)(m*8+e))*DDIM*HDIM, hs, fp.b2[m] + (size_t)e*DDIM,
                      out, (by-8)*64, col0, limit,
                      tok3 + ((size_t)m*NEXP + e)*CAP, gslot3 + ((size_t)m*NEXP + e)*CAP);
    }
}

// ---------- per-model pipelined FFN (Tier B) ----------
__global__ __launch_bounds__(256)
void ffnB_k(const unsigned short* __restrict__ xb,
            const unsigned short* __restrict__ W1T, const float* __restrict__ b1,
            const unsigned short* __restrict__ W2T, const float* __restrict__ b2,
            unsigned short* __restrict__ h0, unsigned short* __restrict__ h1,
            float* __restrict__ out,
            const int* __restrict__ tok, const float* __restrict__ gslot,
            const int* __restrict__ cntk, int eh)
{
    __shared__ __align__(16) short lds[12288];
    const int bx = blockIdx.x, by = blockIdx.y;
    const int col0 = bx * 128;
    if (by < 8){
        if (eh > 7) return;
        int limit = cntk[eh]; if (limit > CAP) limit = CAP;
        if (col0 >= limit) return;
        unsigned short* hd = (eh & 1) ? h1 : h0;
        gemm_core_t<1, 1>(lds, lds + 4096,
                          W1T + (size_t)eh*HDIM*DDIM, xb, b1 + (size_t)eh*HDIM,
                          hd, DDIM, HDIM, by*128, col0, limit,
                          tok + (size_t)eh*CAP, nullptr, nullptr);
    } else {
        int ey = eh - 1; if (ey < 0) return;
        int limit = cntk[ey]; if (limit > CAP) limit = CAP;
        if (col0 >= limit) return;
        const unsigned short* hs = (ey & 1) ? h1 : h0;
        gemm_core_y64(lds, W2T + (size_t)ey*DDIM*HDIM, hs, b2 + (size_t)ey*DDIM,
                      out, (by-8)*64, col0, limit,
                      tok + (size_t)ey*CAP, gslot + (size_t)ey*CAP);
    }
}

// ---------- ranking (batched over 3 models via blockIdx.y) ----------
__global__ __launch_bounds__(1024)
void rank_count3_k(const int* __restrict__ idx3, const int* __restrict__ label,
                   int* __restrict__ bcnt3)
{
    __shared__ int c[NEXP];
    const int m = blockIdx.y;
    const int* idx = idx3 + (size_t)m * NSLOT;
    int t = threadIdx.x;
    if (t < NEXP) c[t] = 0;
    __syncthreads();
    int s = blockIdx.x * 1024 + t;
    int n = s >> 1;
    int e = idx[s];
    bool valid = (m == 0) || (label[n] == m - 1);
    if (valid) atomicAdd(&c[e], 1);
    __syncthreads();
    if (t < NEXP) bcnt3[((size_t)m*128 + blockIdx.x)*NEXP + t] = c[t];
}

__global__ void rank_scan3_k(const int* __restrict__ bcnt3, int* __restrict__ boff3,
                             int* __restrict__ cntk3)
{
    int m = blockIdx.x, e = threadIdx.x;
    if (e < NEXP){
        int run = 0;
        for (int b = 0; b < NSLOT/1024; b++){
            boff3[((size_t)m*128 + b)*NEXP + e] = run;
            run += bcnt3[((size_t)m*128 + b)*NEXP + e];
        }
        cntk3[m*16 + e] = run < CAP ? run : CAP;
    }
}

__global__ __launch_bounds__(1024)
void rank_assign3_k(const int* __restrict__ idx3, const int* __restrict__ label,
                    const int* __restrict__ boff3, const float* __restrict__ gw3,
                    const float* __restrict__ dscale,
                    int* __restrict__ tok3, float* __restrict__ gs3)
{
    __shared__ int wcnt[16][NEXP];
    __shared__ int woff[16][NEXP];
    const int m = blockIdx.y;
    const int* idx = idx3 + (size_t)m * NSLOT;
    const float* gw = gw3 + (size_t)m * NSLOT;
    int t = threadIdx.x;
    int s = blockIdx.x * 1024 + t;
    int n = s >> 1;
    int e = idx[s];
    bool valid = (m == 0) || (label[n] == m - 1);
    int w = t >> 6, lane = t & 63;
    unsigned long long lt = (lane == 0) ? 0ull : ((1ull << lane) - 1ull);
    int myrank = 0;
    #pragma unroll
    for (int ei = 0; ei < NEXP; ei++){
        unsigned long long bal = __ballot(valid && (e == ei));
        if (ei == e) myrank = __popcll(bal & lt);
        if (lane == 0) wcnt[w][ei] = __popcll(bal);
    }
    __syncthreads();
    if (t < NEXP){
        int run = boff3[((size_t)m*128 + blockIdx.x)*NEXP + t];
        for (int w2 = 0; w2 < 16; w2++){
            woff[w2][t] = run;
            run += wcnt[w2][t];
        }
    }
    __syncthreads();
    int pos = woff[w][e] + myrank;
    bool keep = valid && (pos < CAP);
    if (keep){
        float scale = (m > 0) ? dscale[0] : 1.f;
        tok3[((size_t)m*NEXP + e)*CAP + pos] = n;
        gs3[((size_t)m*NEXP + e)*CAP + pos] = gw[s] * scale;
    }
}

extern "C" void kernel_launch(void* const* d_in, const int* in_sizes, int n_in,
                              void* d_out, int out_size, void* d_ws, size_t ws_size,
                              hipStream_t stream)
{
    (void)in_sizes; (void)n_in; (void)out_size;
    const float* x      = (const float*)d_in[0];
    const int*   label  = (const int*)  d_in[1];
    const float* dscale = (const float*)d_in[2];
    float* out = (float*)d_out;

    const size_t XB  = (size_t)NTOK * DDIM * 2;            // 64MB
    const size_t HS  = (size_t)CAP * HDIM * 2;             // 32MB
    const size_t WPT = (size_t)3 * PROJ * DDIM * 2;        // 768KB
    const size_t SS  = (size_t)2 * 3 * NTOK * 4;           // 1.5MB
    const size_t WN  = (size_t)3 * DDIM * 8 * 4;           // 48KB
    const size_t SMALL = WPT + SS + WN + 256 +
                         (size_t)3*PROJ*NEXP*4 +           // simn3
                         (size_t)3*NSLOT*4*2 +             // idx3, gw3
                         (size_t)3*NEXP*CAP*4*2 +          // tok3, gslot3
                         (size_t)3*128*NEXP*4*2 + 256;     // bcnt3, boff3, cntk3
    const size_t W12A = (size_t)2 * 3 * NEXP * DDIM * HDIM * 2;  // 48MB
    const size_t W12B = (size_t)2 * NEXP * DDIM * HDIM * 2;      // 16MB
    const size_t common = XB + HS + SMALL;

    int tier;
    if      (ws_size >= common + HS + W12A) tier = 0;   // cross-model pipeline
    else if (ws_size >= common + HS + W12B) tier = 1;   // per-model pipeline
    else if (ws_size >= common + W12B)      tier = 2;   // per-model serial
    else return;  // clean failure, not a fault

    char* p = (char*)d_ws;
    unsigned short* xb   = (unsigned short*)p; p += XB;
    unsigned short* h0   = (unsigned short*)p; p += HS;
    unsigned short* WpT3 = (unsigned short*)p; p += WPT;
    float* ssbuf = (float*)p;  p += SS;
    float* Wn3   = (float*)p;  p += WN;
    float* bd3   = (float*)p;  p += 256;
    float* simn3 = (float*)p;  p += (size_t)3*PROJ*NEXP*4;
    int*   idx3  = (int*)p;    p += (size_t)3*NSLOT*4;
    float* gw3   = (float*)p;  p += (size_t)3*NSLOT*4;
    int*   tok3  = (int*)p;    p += (size_t)3*NEXP*CAP*4;
    float* gslot3= (float*)p;  p += (size_t)3*NEXP*CAP*4;
    int*   bcnt3 = (int*)p;    p += (size_t)3*128*NEXP*4;
    int*   boff3 = (int*)p;    p += (size_t)3*128*NEXP*4;
    int*   cntk3 = (int*)p;    p += 256;
    unsigned short* h1 = nullptr;
    if (tier <= 1){ h1 = (unsigned short*)p; p += HS; }
    unsigned short* Wbuf = (unsigned short*)p;

    // gather per-model pointer structs
    SimArgs sa; TpArgs ta; WprodArgs wa; PssArgs pa; GfArgs gf; W12P wp; FfnP fp;
    for (int m = 0; m < 3; m++){
        ta.Wp[m] = (const float*)d_in[3 + 8*m + 0];
        wa.Wp[m] = ta.Wp[m];
        wa.bp[m] = (const float*)d_in[3 + 8*m + 1];
        pa.bp[m] = wa.bp[m];
        sa.sim[m] = (const float*)d_in[3 + 8*m + 2];
        gf.tp[m] = (const float*)d_in[3 + 8*m + 3];
        wp.W1[m] = (const float*)d_in[3 + 8*m + 4];
        fp.b1[m] = (const float*)d_in[3 + 8*m + 5];
        wp.W2[m] = (const float*)d_in[3 + 8*m + 6];
        fp.b2[m] = (const float*)d_in[3 + 8*m + 7];
    }

    // ---- prep + gate ----
    zero_k<<<dim3((NTOK*DDIM/4)/256), dim3(256), 0, stream>>>((float4*)out);
    cvt_k<<<dim3(NTOK*DDIM/4/256), dim3(256), 0, stream>>>((const float4*)x, (ushort4*)xb, NTOK*DDIM/4);
    simn3_k<<<dim3(3), dim3(256), 0, stream>>>(sa, simn3);
    transWp_k<<<dim3(PROJ/32, DDIM/32, 3), dim3(32,8), 0, stream>>>(ta, WpT3);
    wprod_k<<<dim3(3), dim3(256), 0, stream>>>(wa, simn3, Wn3, bd3);
    pss_k<<<dim3(2, NTOK/128, 3), dim3(256), 0, stream>>>(WpT3, xb, pa, ssbuf);
    gatefin_k<<<dim3(NTOK/256), dim3(256), 0, stream>>>(x, label, Wn3, bd3, ssbuf, gf, idx3, gw3);

    // ---- ranking (all 3 models) ----
    rank_count3_k<<<dim3(NSLOT/1024, 3), dim3(1024), 0, stream>>>(idx3, label, bcnt3);
    rank_scan3_k<<<dim3(3), dim3(64), 0, stream>>>(bcnt3, boff3, cntk3);
    rank_assign3_k<<<dim3(NSLOT/1024, 3), dim3(1024), 0, stream>>>(
        idx3, label, boff3, gw3, dscale, tok3, gslot3);

    // ---- FFN ----
    if (tier == 0){
        unsigned short* W1T3 = Wbuf;
        unsigned short* W2T3 = Wbuf + (size_t)3*NEXP*DDIM*HDIM;
        transW12all_k<<<dim3(32, 32, 48), dim3(32,8), 0, stream>>>(wp, W1T3, W2T3);
        for (int ge = 0; ge <= 24; ge++)
            ffnA_k<<<dim3(128, 16), 256, 0, stream>>>(
                xb, W1T3, W2T3, fp, h0, h1, out, tok3, gslot3, cntk3, ge);
    } else {
        unsigned short* W1T = Wbuf;
        unsigned short* W2T = Wbuf + (size_t)NEXP*DDIM*HDIM;
        for (int m = 0; m < 3; m++){
            trans2_k<<<dim3(32, 32, 16), dim3(32,8), 0, stream>>>(wp.W1[m], wp.W2[m], W1T, W2T);
            const int* tokm = tok3 + (size_t)m*NEXP*CAP;
            const float* gsm = gslot3 + (size_t)m*NEXP*CAP;
            const int* cntm = cntk3 + m*16;
            if (tier == 1){
                for (int eh = 0; eh <= 8; eh++)
                    ffnB_k<<<dim3(128, 16), 256, 0, stream>>>(
                        xb, W1T, fp.b1[m], W2T, fp.b2[m], h0, h1, out, tokm, gsm, cntm, eh);
            } else {
                for (int e = 0; e < NEXP; e++){
                    mgemm3_k<1, 1><<<dim3(HDIM/128, CAP/128), 256, 0, stream>>>(
                        W1T + (size_t)e*HDIM*DDIM, xb, fp.b1[m] + (size_t)e*HDIM, h0,
                        DDIM, HDIM, tokm + (size_t)e*CAP, nullptr, nullptr, cntm, e);
                    mgemm3_k<0, 3><<<dim3(DDIM/128, CAP/128), 256, 0, stream>>>(
                        W2T + (size_t)e*DDIM*HDIM, h0, fp.b2[m] + (size_t)e*DDIM, out,
                        HDIM, DDIM, nullptr, tokm + (size_t)e*CAP, gsm + (size_t)e*CAP, cntm, e);
                }
            }
        }
    }
}